// Round 1
// baseline (3684.966 us; speedup 1.0000x reference)
//
#include <hip/hip_runtime.h>

#define S_DIM 1024
#define N_DIM 384
#define CZ    128
#define CM    64
#define H_DIM 8
#define CH    32
#define COPM  32
#define HID   256
#define SD    32768   // S_DIM*CH
#define MO    12288   // N_DIM*COPM

typedef __attribute__((ext_vector_type(8))) short  short8;
typedef __attribute__((ext_vector_type(4))) float  floatx4;

__device__ __forceinline__ float bf2f(unsigned short u){
  union { unsigned int u; float f; } v; v.u = ((unsigned int)u)<<16; return v.f;
}
__device__ __forceinline__ unsigned short f2bf(float f){
  union { float f; unsigned int u; } v; v.f = f;
  return (unsigned short)((v.u + 0x7fffu + ((v.u>>16)&1u)) >> 16);
}
__device__ __forceinline__ float red64(float x){
  #pragma unroll
  for (int off=1; off<64; off<<=1) x += __shfl_xor(x, off, 64);
  return x;
}
__device__ __forceinline__ float red16(float x){
  #pragma unroll
  for (int off=1; off<16; off<<=1) x += __shfl_xor(x, off, 64);
  return x;
}
__device__ __forceinline__ void gload16(const void* g, void* l){
  __builtin_amdgcn_global_load_lds((__attribute__((address_space(1))) void*)(g),
                                   (__attribute__((address_space(3))) void*)(l), 16, 0, 0);
}

// ---------------- prep: w_out -> bf16 [128][1024] ----------------
__global__ void kprep(const float* __restrict__ w, unsigned short* __restrict__ o){
  int i = blockIdx.x*256 + threadIdx.x;
  o[i] = f2bf(w[i]);
}

// ---------------- K1: logits[h][i][j] = LN(z)@wz^T + mask ----------------
__global__ __launch_bounds__(256) void k1_logits(
    const float* __restrict__ z, const float* __restrict__ tm,
    const float* __restrict__ g, const float* __restrict__ b,
    const float* __restrict__ wz, float* __restrict__ logits)
{
  int idx  = blockIdx.x*4 + (threadIdx.x>>6);      // (i,j) flat, 147456
  int lane = threadIdx.x & 63;
  const float* zp = z + (size_t)idx*CZ;
  float x0 = zp[lane], x1 = zp[lane+64];
  float mu = red64(x0+x1) * (1.0f/128.0f);
  float d0 = x0-mu, d1 = x1-mu;
  float var = red64(d0*d0 + d1*d1) * (1.0f/128.0f);
  float rs = rsqrtf(var + 1e-5f);
  float y0 = d0*rs*g[lane]    + b[lane];
  float y1 = d1*rs*g[lane+64] + b[lane+64];
  float mterm = (1.0f - tm[idx]) * (-1e6f);
  #pragma unroll
  for (int h=0; h<H_DIM; ++h){
    float p = y0*wz[h*CZ+lane] + y1*wz[h*CZ+64+lane];
    p = red64(p);
    if (lane==0) logits[(size_t)h*N_DIM*N_DIM + idx] = p + mterm;
  }
}

// ---------------- K2: softmax rows -> w_att bf16 ----------------
__global__ __launch_bounds__(256) void k2_softmax(
    const float* __restrict__ logits, unsigned short* __restrict__ watt)
{
  int row  = blockIdx.x*4 + (threadIdx.x>>6);      // 3072 rows (h*384+i)
  int lane = threadIdx.x & 63;
  const float* p = logits + (size_t)row*N_DIM;
  float v[6]; float mx = -3.4e38f;
  #pragma unroll
  for (int e=0;e<6;++e){ v[e] = p[lane + e*64]; mx = fmaxf(mx, v[e]); }
  #pragma unroll
  for (int off=1; off<64; off<<=1) mx = fmaxf(mx, __shfl_xor(mx, off, 64));
  float sum = 0.f;
  #pragma unroll
  for (int e=0;e<6;++e){ v[e] = __expf(v[e]-mx); sum += v[e]; }
  sum = red64(sum);
  float inv = 1.0f/sum;
  #pragma unroll
  for (int e=0;e<6;++e) watt[(size_t)row*N_DIM + lane + e*64] = f2bf(v[e]*inv);
}

// ---------------- K3: mn = LN(m) (bf16), v2[h][(s,d)][j] = mn@wm^T ----------------
__global__ __launch_bounds__(256) void k3_lnm_v(
    const float* __restrict__ m, const float* __restrict__ g, const float* __restrict__ b,
    const float* __restrict__ wm, unsigned short* __restrict__ mn, unsigned short* __restrict__ v2)
{
  __shared__ float mnL[16*64];
  int s = blockIdx.y, j0 = blockIdx.x*16, t = threadIdx.x;
  {
    int r = t>>4, q = t&15;
    size_t row = (size_t)s*N_DIM + j0 + r;
    float4 x = *(const float4*)(m + row*CM + q*4);
    float mu = red16(x.x+x.y+x.z+x.w) * (1.0f/64.0f);
    float4 d = {x.x-mu, x.y-mu, x.z-mu, x.w-mu};
    float var = red16(d.x*d.x+d.y*d.y+d.z*d.z+d.w*d.w) * (1.0f/64.0f);
    float rs = rsqrtf(var + 1e-5f);
    float4 y;
    y.x = d.x*rs*g[q*4+0] + b[q*4+0];
    y.y = d.y*rs*g[q*4+1] + b[q*4+1];
    y.z = d.z*rs*g[q*4+2] + b[q*4+2];
    y.w = d.w*rs*g[q*4+3] + b[q*4+3];
    mnL[r*64+q*4+0]=y.x; mnL[r*64+q*4+1]=y.y; mnL[r*64+q*4+2]=y.z; mnL[r*64+q*4+3]=y.w;
    ushort4 u4 = {f2bf(y.x), f2bf(y.y), f2bf(y.z), f2bf(y.w)};
    *(ushort4*)(mn + row*CM + q*4) = u4;
  }
  __syncthreads();
  float acc[16];
  #pragma unroll
  for (int r=0;r<16;++r) acc[r]=0.f;
  const float4* wm4  = (const float4*)wm;
  const float4* mnL4 = (const float4*)mnL;
  #pragma unroll 4
  for (int c4=0;c4<16;++c4){
    float4 w = wm4[t*16 + c4];
    #pragma unroll
    for (int r=0;r<16;++r){
      float4 x = mnL4[r*16 + c4];
      acc[r] += x.x*w.x + x.y*w.y + x.z*w.z + x.w*w.w;
    }
  }
  int h = t>>5, d2 = t&31;
  short8 p0, p1;
  #pragma unroll
  for (int e=0;e<8;++e){ p0[e] = (short)f2bf(acc[e]); p1[e] = (short)f2bf(acc[8+e]); }
  unsigned short* dst = v2 + ((size_t)h*SD + (size_t)s*CH + d2)*N_DIM + j0;
  *(short8*)dst       = p0;
  *(short8*)(dst + 8) = p1;
}

// ---------------- K7: num[i][j] = max(1, sum_s mask[s,i]*mask[s,j]) ----------------
__global__ __launch_bounds__(256) void k7_num(
    const float* __restrict__ mask, float* __restrict__ num)
{
  __shared__ float mA[64*16], mB[64*16];
  int i0 = blockIdx.y*16, j0 = blockIdx.x*16, t = threadIdx.x;
  int ti = t>>4, tj = t&15;
  float acc = 0.f;
  for (int s0=0; s0<S_DIM; s0+=64){
    #pragma unroll
    for (int k=0;k<4;++k){
      int idx = t + k*256; int ss = idx>>4, c = idx&15;
      mA[idx] = mask[(size_t)(s0+ss)*N_DIM + i0 + c];
      mB[idx] = mask[(size_t)(s0+ss)*N_DIM + j0 + c];
    }
    __syncthreads();
    #pragma unroll 8
    for (int ss=0; ss<64; ++ss) acc += mA[ss*16+ti] * mB[ss*16+tj];
    __syncthreads();
  }
  num[(size_t)(i0+ti)*N_DIM + j0+tj] = fmaxf(acc, 1.0f);
}

// ---------------- shared 128x128 A*B^T core (m97 pattern) ----------------
__device__ __forceinline__ void gemm_bt_core(
    const unsigned short* __restrict__ A, const unsigned short* __restrict__ B,
    int lda, int ldb, int K,
    unsigned short* As, unsigned short* Bs, floatx4 acc[4][4],
    int wr, int wc, int ln15, int quad)
{
  int t = threadIdx.x;
  for (int k0=0; k0<K; k0+=64){
    #pragma unroll
    for (int it=0; it<4; ++it){
      int ch = it*256 + t;                  // 1024 chunks of 16B per operand
      int row = ch>>3, koff = (ch&7)*8;
      gload16(A + (size_t)row*lda + k0 + koff, As + ch*8);
      gload16(B + (size_t)row*ldb + k0 + koff, Bs + ch*8);
    }
    __syncthreads();
    #pragma unroll
    for (int kk=0; kk<2; ++kk){
      short8 af[4], bfr[4];
      #pragma unroll
      for (int x=0;x<4;++x) af[x]  = *(const short8*)(As + ((wr + x*16 + ln15)<<6) + kk*32 + quad*8);
      #pragma unroll
      for (int x=0;x<4;++x) bfr[x] = *(const short8*)(Bs + ((wc + x*16 + ln15)<<6) + kk*32 + quad*8);
      #pragma unroll
      for (int ti=0;ti<4;++ti)
        #pragma unroll
        for (int tj=0;tj<4;++tj)
          acc[ti][tj] = __builtin_amdgcn_mfma_f32_16x16x32_bf16(af[ti], bfr[tj], acc[ti][tj], 0, 0, 0);
    }
    __syncthreads();
  }
}

// ---------------- K4: per-head attention o2[h][i][(s,d)] = att @ v2^T ----------------
__global__ __launch_bounds__(256) void k4_attn(
    const unsigned short* __restrict__ watt, const unsigned short* __restrict__ v2,
    unsigned short* __restrict__ o2)
{
  __shared__ unsigned short smem[16384];
  int t = threadIdx.x, lane = t&63, w = t>>6;
  int ln15 = lane&15, quad = lane>>4;
  int wr = (w>>1)*64, wc = (w&1)*64;
  int nb = blockIdx.x, mb = blockIdx.y, h = blockIdx.z;
  const unsigned short* A = watt + (size_t)h*N_DIM*N_DIM + (size_t)(mb*128)*N_DIM;
  const unsigned short* B = v2 + ((size_t)h*SD + (size_t)nb*128)*N_DIM;
  floatx4 acc[4][4];
  #pragma unroll
  for (int ti=0;ti<4;++ti)
    #pragma unroll
    for (int tj=0;tj<4;++tj) acc[ti][tj] = (floatx4){0.f,0.f,0.f,0.f};
  gemm_bt_core(A, B, N_DIM, N_DIM, N_DIM, smem, smem+8192, acc, wr, wc, ln15, quad);
  unsigned short* C = o2 + ((size_t)h*N_DIM + mb*128)*SD + nb*128;
  #pragma unroll
  for (int ti=0;ti<4;++ti)
    #pragma unroll
    for (int tj=0;tj<4;++tj)
      #pragma unroll
      for (int r=0;r<4;++r)
        C[(size_t)(wr+ti*16+quad*4+r)*SD + wc + tj*16 + ln15] = f2bf(acc[ti][tj][r]);
}

// ---------------- K5: m1 = m + (sigmoid(mn@wg^T) * o) @ wo^T ----------------
__global__ __launch_bounds__(256) void k5_pwa(
    const float* __restrict__ m_in, const unsigned short* __restrict__ mn,
    const unsigned short* __restrict__ o2,
    const float* __restrict__ wg, const float* __restrict__ wo,
    float* __restrict__ m1_out)
{
  __shared__ float mnL[16*64];
  __shared__ float goL[16*256];
  int s = blockIdx.y, i0 = blockIdx.x*16, t = threadIdx.x;
  {
    int r = t>>4, c = (t&15)*4;
    ushort4 u = *(const ushort4*)(mn + ((size_t)s*N_DIM + i0 + r)*CM + c);
    mnL[r*64+c+0]=bf2f(u.x); mnL[r*64+c+1]=bf2f(u.y);
    mnL[r*64+c+2]=bf2f(u.z); mnL[r*64+c+3]=bf2f(u.w);
  }
  __syncthreads();
  float accG[16];
  #pragma unroll
  for (int r=0;r<16;++r) accG[r]=0.f;
  const float4* wg4  = (const float4*)wg;
  const float4* mnL4 = (const float4*)mnL;
  #pragma unroll 4
  for (int c4=0;c4<16;++c4){
    float4 w = wg4[t*16+c4];
    #pragma unroll
    for (int r=0;r<16;++r){
      float4 x = mnL4[r*16+c4];
      accG[r] += x.x*w.x + x.y*w.y + x.z*w.z + x.w*w.w;
    }
  }
  int h = t>>5, d = t&31;
  #pragma unroll
  for (int r=0;r<16;++r){
    float gv = 1.f/(1.f+__expf(-accG[r]));
    float ov = bf2f(o2[((size_t)h*N_DIM + (i0+r))*SD + (size_t)s*CH + d]);
    goL[r*256+t] = gv*ov;
  }
  __syncthreads();
  int c = t&63, rg = t>>6;
  float acc[4] = {0.f,0.f,0.f,0.f};
  const float4* wo4  = (const float4*)wo;
  const float4* goL4 = (const float4*)goL;
  #pragma unroll 8
  for (int k4=0;k4<64;++k4){
    float4 w = wo4[c*64+k4];
    #pragma unroll
    for (int rr=0;rr<4;++rr){
      float4 x = goL4[(rg*4+rr)*64+k4];
      acc[rr] += x.x*w.x + x.y*w.y + x.z*w.z + x.w*w.w;
    }
  }
  #pragma unroll
  for (int rr=0;rr<4;++rr){
    int r = rg*4+rr;
    size_t idx = ((size_t)s*N_DIM + i0 + r)*CM + c;
    m1_out[idx] = m_in[idx] + acc[rr];
  }
}

// ---------------- K6: SwiGLU transition (in-place on m1) + a/b projections ----------------
__global__ __launch_bounds__(256) void k6_trans(
    float* __restrict__ m_io, const float* __restrict__ mask,
    const float* __restrict__ lntg, const float* __restrict__ lntb,
    const float* __restrict__ fc1, const float* __restrict__ fc2, const float* __restrict__ fc3,
    const float* __restrict__ lnog, const float* __restrict__ lnob,
    const float* __restrict__ wa, const float* __restrict__ wb,
    unsigned short* __restrict__ a2, unsigned short* __restrict__ b2)
{
  __shared__ float mL[16*64];
  __shared__ float tL[16*64];
  __shared__ float uL[16*256];
  __shared__ float maskL[16];
  int i = blockIdx.y, s0 = blockIdx.x*16, t = threadIdx.x;
  int r = t>>4, q = t&15;
  { // load m1 rows (s0+r, i), LN -> tL, raw -> mL
    float4 x = *(const float4*)(m_io + ((size_t)(s0+r)*N_DIM + i)*CM + q*4);
    float mu = red16(x.x+x.y+x.z+x.w) * (1.0f/64.f);
    float4 d = {x.x-mu,x.y-mu,x.z-mu,x.w-mu};
    float var = red16(d.x*d.x+d.y*d.y+d.z*d.z+d.w*d.w)*(1.0f/64.f);
    float rs = rsqrtf(var+1e-5f);
    mL[r*64+q*4+0]=x.x; mL[r*64+q*4+1]=x.y; mL[r*64+q*4+2]=x.z; mL[r*64+q*4+3]=x.w;
    tL[r*64+q*4+0]=d.x*rs*lntg[q*4+0]+lntb[q*4+0];
    tL[r*64+q*4+1]=d.y*rs*lntg[q*4+1]+lntb[q*4+1];
    tL[r*64+q*4+2]=d.z*rs*lntg[q*4+2]+lntb[q*4+2];
    tL[r*64+q*4+3]=d.w*rs*lntg[q*4+3]+lntb[q*4+3];
    if (t < 16) maskL[t] = mask[(size_t)(s0+t)*N_DIM + i];
  }
  __syncthreads();
  { // hidden: k = t; uL = silu(t@fc1^T) * (t@fc2^T)
    float H1[16], H2[16];
    #pragma unroll
    for (int r2=0;r2<16;++r2){ H1[r2]=0.f; H2[r2]=0.f; }
    const float4* f1 = (const float4*)fc1;
    const float4* f2 = (const float4*)fc2;
    const float4* tL4 = (const float4*)tL;
    #pragma unroll 4
    for (int c4=0;c4<16;++c4){
      float4 w1 = f1[t*16+c4], w2 = f2[t*16+c4];
      #pragma unroll
      for (int r2=0;r2<16;++r2){
        float4 x = tL4[r2*16+c4];
        H1[r2] += x.x*w1.x + x.y*w1.y + x.z*w1.z + x.w*w1.w;
        H2[r2] += x.x*w2.x + x.y*w2.y + x.z*w2.z + x.w*w2.w;
      }
    }
    #pragma unroll
    for (int r2=0;r2<16;++r2){
      float h1v = H1[r2];
      uL[r2*256+t] = h1v/(1.f+__expf(-h1v))*H2[r2];
    }
  }
  __syncthreads();
  { // m2 = m1 + u@fc3^T ; write out + keep in tL
    int c = t&63, rg = t>>6;
    float acc[4]={0.f,0.f,0.f,0.f};
    const float4* f3  = (const float4*)fc3;
    const float4* uL4 = (const float4*)uL;
    #pragma unroll 8
    for (int k4=0;k4<64;++k4){
      float4 w = f3[c*64+k4];
      #pragma unroll
      for (int rr=0;rr<4;++rr){
        float4 x = uL4[(rg*4+rr)*64+k4];
        acc[rr] += x.x*w.x + x.y*w.y + x.z*w.z + x.w*w.w;
      }
    }
    #pragma unroll
    for (int rr=0;rr<4;++rr){
      int r2 = rg*4+rr;
      float m2v = mL[r2*64+c] + acc[rr];
      m_io[((size_t)(s0+r2)*N_DIM+i)*CM + c] = m2v;
      tL[r2*64+c] = m2v;
    }
  }
  __syncthreads();
  { // mo = LN(m2) -> mL
    const float4* tL4 = (const float4*)tL;
    float4 x = tL4[r*16+q];
    float mu = red16(x.x+x.y+x.z+x.w) * (1.0f/64.f);
    float4 d = {x.x-mu,x.y-mu,x.z-mu,x.w-mu};
    float var = red16(d.x*d.x+d.y*d.y+d.z*d.z+d.w*d.w)*(1.0f/64.f);
    float rs = rsqrtf(var+1e-5f);
    mL[r*64+q*4+0]=d.x*rs*lnog[q*4+0]+lnob[q*4+0];
    mL[r*64+q*4+1]=d.y*rs*lnog[q*4+1]+lnob[q*4+1];
    mL[r*64+q*4+2]=d.z*rs*lnog[q*4+2]+lnob[q*4+2];
    mL[r*64+q*4+3]=d.w*rs*lnog[q*4+3]+lnob[q*4+3];
  }
  __syncthreads();
  { // a,b projections, transposed store a2[(i*32+c2)][s]
    int rr = t&15, c2 = t>>4;
    float a0=0.f,a1=0.f,b0=0.f,b1=0.f;
    const float4* wa4 = (const float4*)wa;
    const float4* wb4 = (const float4*)wb;
    const float4* mo4 = (const float4*)mL;
    #pragma unroll 4
    for (int c4=0;c4<16;++c4){
      float4 x = mo4[rr*16+c4];
      float4 wA0 = wa4[c2*16+c4], wA1 = wa4[(c2+16)*16+c4];
      float4 wB0 = wb4[c2*16+c4], wB1 = wb4[(c2+16)*16+c4];
      a0 += x.x*wA0.x + x.y*wA0.y + x.z*wA0.z + x.w*wA0.w;
      a1 += x.x*wA1.x + x.y*wA1.y + x.z*wA1.z + x.w*wA1.w;
      b0 += x.x*wB0.x + x.y*wB0.y + x.z*wB0.z + x.w*wB0.w;
      b1 += x.x*wB1.x + x.y*wB1.y + x.z*wB1.z + x.w*wB1.w;
    }
    float mk = maskL[rr];
    size_t sidx = (size_t)(s0 + rr);
    a2[((size_t)i*COPM + c2)*S_DIM + sidx]      = f2bf(a0*mk);
    a2[((size_t)i*COPM + c2+16)*S_DIM + sidx]   = f2bf(a1*mk);
    b2[((size_t)i*COPM + c2)*S_DIM + sidx]      = f2bf(b0*mk);
    b2[((size_t)i*COPM + c2+16)*S_DIM + sidx]   = f2bf(b1*mk);
  }
}

// ---------------- K8: outer-product GEMM + fused w_out epilogue -> z ----------------
__global__ __launch_bounds__(256) void k8_outer(
    const unsigned short* __restrict__ a2, const unsigned short* __restrict__ b2,
    const unsigned short* __restrict__ woutb, const float* __restrict__ num,
    const float* __restrict__ zin, const float* __restrict__ bout,
    float* __restrict__ zout)
{
  __shared__ unsigned short smem[16384];
  int t = threadIdx.x, lane = t&63, w = t>>6;
  int ln15 = lane&15, quad = lane>>4;
  int wr = (w>>1)*64, wc = (w&1)*64;
  int nb = blockIdx.x, mb = blockIdx.y;
  const unsigned short* A = a2 + (size_t)(mb*128)*S_DIM;
  const unsigned short* B = b2 + (size_t)(nb*128)*S_DIM;
  floatx4 acc[4][4];
  #pragma unroll
  for (int ti=0;ti<4;++ti)
    #pragma unroll
    for (int tj=0;tj<4;++tj) acc[ti][tj] = (floatx4){0.f,0.f,0.f,0.f};
  gemm_bt_core(A, B, S_DIM, S_DIM, S_DIM, smem, smem+8192, acc, wr, wc, ln15, quad);
  // dump tile to LDS as bf16 P[128][128] (staging buffers are dead; last op was a barrier)
  unsigned short* P = smem;
  #pragma unroll
  for (int ti=0;ti<4;++ti)
    #pragma unroll
    for (int tj=0;tj<4;++tj)
      #pragma unroll
      for (int r=0;r<4;++r)
        P[(wr+ti*16+quad*4+r)*128 + wc+tj*16+ln15] = f2bf(acc[ti][tj][r]);
  __syncthreads();
  // epilogue: C2[pair(16) x cz(128)] = P(16x1024 view) @ w_out^T, K=1024
  int i0 = mb*4, j0 = nb*4;
  #pragma unroll
  for (int e=0; e<2; ++e){
    int czt = w*2+e;
    floatx4 acc2 = (floatx4){0.f,0.f,0.f,0.f};
    #pragma unroll 8
    for (int ks=0; ks<32; ++ks){
      // A-frag: m=pair=ln15 -> (ic=ln15>>2, jc=ln15&3); k -> (c=ks, d=quad*8+j)
      short8 pa = *(const short8*)(P + (((ln15>>2)*32 + ks)<<7) + (ln15&3)*32 + quad*8);
      // B-frag: n=cz=czt*16+ln15, 8 contiguous k from w_out[cz][k]
      short8 wf = *(const short8*)(woutb + (size_t)(czt*16+ln15)*1024 + ks*32 + quad*8);
      acc2 = __builtin_amdgcn_mfma_f32_16x16x32_bf16(pa, wf, acc2, 0, 0, 0);
    }
    #pragma unroll
    for (int r2=0;r2<4;++r2){
      int p = quad*4+r2, ic = p>>2, jc = p&3;
      int i = i0+ic, j = j0+jc;
      float nv = num[(size_t)i*N_DIM+j];
      size_t zi = ((size_t)i*N_DIM + j)*CZ + czt*16 + ln15;
      zout[zi] = zin[zi] + acc2[r2]*(1.0f/nv) + bout[czt*16+ln15];
    }
  }
}

extern "C" void kernel_launch(void* const* d_in, const int* in_sizes, int n_in,
                              void* d_out, int out_size, void* d_ws, size_t ws_size,
                              hipStream_t stream)
{
  const float* z    = (const float*)d_in[0];
  const float* m    = (const float*)d_in[1];
  const float* tm   = (const float*)d_in[2];
  const float* mask = (const float*)d_in[3];
  const float* lnzg = (const float*)d_in[4];
  const float* lnzb = (const float*)d_in[5];
  const float* wz   = (const float*)d_in[6];
  const float* lnmg = (const float*)d_in[7];
  const float* lnmb = (const float*)d_in[8];
  const float* wm   = (const float*)d_in[9];
  const float* wg   = (const float*)d_in[10];
  const float* wo   = (const float*)d_in[11];
  const float* lntg = (const float*)d_in[12];
  const float* lntb = (const float*)d_in[13];
  const float* fc1  = (const float*)d_in[14];
  const float* fc2  = (const float*)d_in[15];
  const float* fc3  = (const float*)d_in[16];
  const float* lnog = (const float*)d_in[17];
  const float* lnob = (const float*)d_in[18];
  const float* wa   = (const float*)d_in[19];
  const float* wb   = (const float*)d_in[20];
  const float* wout = (const float*)d_in[21];
  const float* bout = (const float*)d_in[22];

  float* zout = (float*)d_out;
  float* mout = zout + (size_t)N_DIM*N_DIM*CZ;

  // z-region of d_out doubles as scratch for buffers dead before k8 writes z:
  char* zs = (char*)d_out;
  unsigned short* mn   = (unsigned short*)zs;                 // 50,331,648 B
  float*          logits = (float*)(zs + 50331648);           //  4,718,592 B
  unsigned short* watt = (unsigned short*)(zs + 55050240);    //  2,359,296 B (<= 75.5 MB z region)

  char* ws = (char*)d_ws;
  unsigned short* v2    = (unsigned short*)ws;                // 201,326,592 B
  unsigned short* o2    = (unsigned short*)(ws + 201326592);  // 201,326,592 B
  float*          num   = (float*)(ws + 402653184);           //     589,824 B
  unsigned short* woutb = (unsigned short*)(ws + 403243008);  //     262,144 B
  unsigned short* a2 = v2;                                    // alias: v2 dead after k4
  unsigned short* b2 = v2 + (size_t)MO*S_DIM;

  kprep      <<<512, 256, 0, stream>>>(wout, woutb);
  k1_logits  <<<36864, 256, 0, stream>>>(z, tm, lnzg, lnzb, wz, logits);
  k2_softmax <<<768, 256, 0, stream>>>(logits, watt);
  k3_lnm_v   <<<dim3(24,1024), 256, 0, stream>>>(m, lnmg, lnmb, wm, mn, v2);
  k7_num     <<<dim3(24,24), 256, 0, stream>>>(mask, num);
  k4_attn    <<<dim3(256,3,8), 256, 0, stream>>>(watt, v2, o2);
  k5_pwa     <<<dim3(24,1024), 256, 0, stream>>>(m, mn, o2, wg, wo, mout);
  k6_trans   <<<dim3(64,384), 256, 0, stream>>>(mout, mask, lntg, lntb, fc1, fc2, fc3,
                                                lnog, lnob, wa, wb, a2, b2);
  k8_outer   <<<dim3(96,96), 256, 0, stream>>>(a2, b2, woutb, num, z, bout, zout);
}

// Round 2
// 2036.351 us; speedup vs baseline: 1.8096x; 1.8096x over previous
//
#include <hip/hip_runtime.h>

#define S_DIM 1024
#define N_DIM 384
#define CZ    128
#define CM    64
#define H_DIM 8
#define CH    32
#define COPM  32
#define HID   256
#define SD    32768   // S_DIM*CH
#define MO    12288   // N_DIM*COPM
#define LDSW  72      // padded LDS row stride (ushorts), 144B = 16B-aligned

typedef __attribute__((ext_vector_type(8))) short  short8;
typedef __attribute__((ext_vector_type(4))) float  floatx4;

__device__ __forceinline__ float bf2f(unsigned short u){
  union { unsigned int u; float f; } v; v.u = ((unsigned int)u)<<16; return v.f;
}
__device__ __forceinline__ unsigned short f2bf(float f){
  union { float f; unsigned int u; } v; v.f = f;
  return (unsigned short)((v.u + 0x7fffu + ((v.u>>16)&1u)) >> 16);
}
__device__ __forceinline__ float red64(float x){
  #pragma unroll
  for (int off=1; off<64; off<<=1) x += __shfl_xor(x, off, 64);
  return x;
}
__device__ __forceinline__ float red16(float x){
  #pragma unroll
  for (int off=1; off<16; off<<=1) x += __shfl_xor(x, off, 64);
  return x;
}
__device__ __forceinline__ void gload16(const void* g, void* l){
  __builtin_amdgcn_global_load_lds((__attribute__((address_space(1))) void*)(g),
                                   (__attribute__((address_space(3))) void*)(l), 16, 0, 0);
}

// ---------------- generic fp32 -> bf16 convert ----------------
__global__ void kcvt(const float* __restrict__ w, unsigned short* __restrict__ o, int n){
  int i = blockIdx.x*256 + threadIdx.x;
  if (i < n) o[i] = f2bf(w[i]);
}

// ---------------- K1: logits[h][i][j] = LN(z)@wz^T + mask ----------------
__global__ __launch_bounds__(256) void k1_logits(
    const float* __restrict__ z, const float* __restrict__ tm,
    const float* __restrict__ g, const float* __restrict__ b,
    const float* __restrict__ wz, float* __restrict__ logits)
{
  int idx  = blockIdx.x*4 + (threadIdx.x>>6);      // (i,j) flat, 147456
  int lane = threadIdx.x & 63;
  const float* zp = z + (size_t)idx*CZ;
  float x0 = zp[lane], x1 = zp[lane+64];
  float mu = red64(x0+x1) * (1.0f/128.0f);
  float d0 = x0-mu, d1 = x1-mu;
  float var = red64(d0*d0 + d1*d1) * (1.0f/128.0f);
  float rs = rsqrtf(var + 1e-5f);
  float y0 = d0*rs*g[lane]    + b[lane];
  float y1 = d1*rs*g[lane+64] + b[lane+64];
  float mterm = (1.0f - tm[idx]) * (-1e6f);
  #pragma unroll
  for (int h=0; h<H_DIM; ++h){
    float p = y0*wz[h*CZ+lane] + y1*wz[h*CZ+64+lane];
    p = red64(p);
    if (lane==0) logits[(size_t)h*N_DIM*N_DIM + idx] = p + mterm;
  }
}

// ---------------- K2: softmax rows -> w_att bf16 ----------------
__global__ __launch_bounds__(256) void k2_softmax(
    const float* __restrict__ logits, unsigned short* __restrict__ watt)
{
  int row  = blockIdx.x*4 + (threadIdx.x>>6);      // 3072 rows (h*384+i)
  int lane = threadIdx.x & 63;
  const float* p = logits + (size_t)row*N_DIM;
  float v[6]; float mx = -3.4e38f;
  #pragma unroll
  for (int e=0;e<6;++e){ v[e] = p[lane + e*64]; mx = fmaxf(mx, v[e]); }
  #pragma unroll
  for (int off=1; off<64; off<<=1) mx = fmaxf(mx, __shfl_xor(mx, off, 64));
  float sum = 0.f;
  #pragma unroll
  for (int e=0;e<6;++e){ v[e] = __expf(v[e]-mx); sum += v[e]; }
  sum = red64(sum);
  float inv = 1.0f/sum;
  #pragma unroll
  for (int e=0;e<6;++e) watt[(size_t)row*N_DIM + lane + e*64] = f2bf(v[e]*inv);
}

// ---------------- K3: mn = LN(m) (bf16), v2[h][(s,d)][j] = mn@wm^T ----------------
__global__ __launch_bounds__(256) void k3_lnm_v(
    const float* __restrict__ m, const float* __restrict__ g, const float* __restrict__ b,
    const float* __restrict__ wm, unsigned short* __restrict__ mn, unsigned short* __restrict__ v2)
{
  __shared__ float mnL[16*64];
  int s = blockIdx.y, j0 = blockIdx.x*16, t = threadIdx.x;
  {
    int r = t>>4, q = t&15;
    size_t row = (size_t)s*N_DIM + j0 + r;
    float4 x = *(const float4*)(m + row*CM + q*4);
    float mu = red16(x.x+x.y+x.z+x.w) * (1.0f/64.0f);
    float4 d = {x.x-mu, x.y-mu, x.z-mu, x.w-mu};
    float var = red16(d.x*d.x+d.y*d.y+d.z*d.z+d.w*d.w) * (1.0f/64.0f);
    float rs = rsqrtf(var + 1e-5f);
    float4 y;
    y.x = d.x*rs*g[q*4+0] + b[q*4+0];
    y.y = d.y*rs*g[q*4+1] + b[q*4+1];
    y.z = d.z*rs*g[q*4+2] + b[q*4+2];
    y.w = d.w*rs*g[q*4+3] + b[q*4+3];
    mnL[r*64+q*4+0]=y.x; mnL[r*64+q*4+1]=y.y; mnL[r*64+q*4+2]=y.z; mnL[r*64+q*4+3]=y.w;
    ushort4 u4 = {f2bf(y.x), f2bf(y.y), f2bf(y.z), f2bf(y.w)};
    *(ushort4*)(mn + row*CM + q*4) = u4;
  }
  __syncthreads();
  float acc[16];
  #pragma unroll
  for (int r=0;r<16;++r) acc[r]=0.f;
  const float4* wm4  = (const float4*)wm;
  const float4* mnL4 = (const float4*)mnL;
  #pragma unroll 4
  for (int c4=0;c4<16;++c4){
    float4 w = wm4[t*16 + c4];
    #pragma unroll
    for (int r=0;r<16;++r){
      float4 x = mnL4[r*16 + c4];
      acc[r] += x.x*w.x + x.y*w.y + x.z*w.z + x.w*w.w;
    }
  }
  int h = t>>5, d2 = t&31;
  short8 p0, p1;
  #pragma unroll
  for (int e=0;e<8;++e){ p0[e] = (short)f2bf(acc[e]); p1[e] = (short)f2bf(acc[8+e]); }
  unsigned short* dst = v2 + ((size_t)h*SD + (size_t)s*CH + d2)*N_DIM + j0;
  *(short8*)dst       = p0;
  *(short8*)(dst + 8) = p1;
}

// ---------------- K7: num[i][j] = max(1, sum_s mask[s,i]*mask[s,j]) ----------------
__global__ __launch_bounds__(256) void k7_num(
    const float* __restrict__ mask, float* __restrict__ num)
{
  __shared__ float mA[64*16], mB[64*16];
  int i0 = blockIdx.y*16, j0 = blockIdx.x*16, t = threadIdx.x;
  int ti = t>>4, tj = t&15;
  float acc = 0.f;
  for (int s0=0; s0<S_DIM; s0+=64){
    #pragma unroll
    for (int k=0;k<4;++k){
      int idx = t + k*256; int ss = idx>>4, c = idx&15;
      mA[idx] = mask[(size_t)(s0+ss)*N_DIM + i0 + c];
      mB[idx] = mask[(size_t)(s0+ss)*N_DIM + j0 + c];
    }
    __syncthreads();
    #pragma unroll 8
    for (int ss=0; ss<64; ++ss) acc += mA[ss*16+ti] * mB[ss*16+tj];
    __syncthreads();
  }
  num[(size_t)(i0+ti)*N_DIM + j0+tj] = fmaxf(acc, 1.0f);
}

// ---------------- shared 128x128 A*B^T core (m97 pattern) ----------------
__device__ __forceinline__ void gemm_bt_core(
    const unsigned short* __restrict__ A, const unsigned short* __restrict__ B,
    int lda, int ldb, int K,
    unsigned short* As, unsigned short* Bs, floatx4 acc[4][4],
    int wr, int wc, int ln15, int quad)
{
  int t = threadIdx.x;
  for (int k0=0; k0<K; k0+=64){
    #pragma unroll
    for (int it=0; it<4; ++it){
      int ch = it*256 + t;                  // 1024 chunks of 16B per operand
      int row = ch>>3, koff = (ch&7)*8;
      gload16(A + (size_t)row*lda + k0 + koff, As + ch*8);
      gload16(B + (size_t)row*ldb + k0 + koff, Bs + ch*8);
    }
    __syncthreads();
    #pragma unroll
    for (int kk=0; kk<2; ++kk){
      short8 af[4], bfr[4];
      #pragma unroll
      for (int x=0;x<4;++x) af[x]  = *(const short8*)(As + ((wr + x*16 + ln15)<<6) + kk*32 + quad*8);
      #pragma unroll
      for (int x=0;x<4;++x) bfr[x] = *(const short8*)(Bs + ((wc + x*16 + ln15)<<6) + kk*32 + quad*8);
      #pragma unroll
      for (int ti=0;ti<4;++ti)
        #pragma unroll
        for (int tj=0;tj<4;++tj)
          acc[ti][tj] = __builtin_amdgcn_mfma_f32_16x16x32_bf16(af[ti], bfr[tj], acc[ti][tj], 0, 0, 0);
    }
    __syncthreads();
  }
}

// ---------------- K4: per-head attention o2[h][i][(s,d)] = att @ v2^T ----------------
__global__ __launch_bounds__(256) void k4_attn(
    const unsigned short* __restrict__ watt, const unsigned short* __restrict__ v2,
    unsigned short* __restrict__ o2)
{
  __shared__ unsigned short smem[16384];
  int t = threadIdx.x, lane = t&63, w = t>>6;
  int ln15 = lane&15, quad = lane>>4;
  int wr = (w>>1)*64, wc = (w&1)*64;
  int nb = blockIdx.x, mb = blockIdx.y, h = blockIdx.z;
  const unsigned short* A = watt + (size_t)h*N_DIM*N_DIM + (size_t)(mb*128)*N_DIM;
  const unsigned short* B = v2 + ((size_t)h*SD + (size_t)nb*128)*N_DIM;
  floatx4 acc[4][4];
  #pragma unroll
  for (int ti=0;ti<4;++ti)
    #pragma unroll
    for (int tj=0;tj<4;++tj) acc[ti][tj] = (floatx4){0.f,0.f,0.f,0.f};
  gemm_bt_core(A, B, N_DIM, N_DIM, N_DIM, smem, smem+8192, acc, wr, wc, ln15, quad);
  unsigned short* C = o2 + ((size_t)h*N_DIM + mb*128)*SD + nb*128;
  #pragma unroll
  for (int ti=0;ti<4;++ti)
    #pragma unroll
    for (int tj=0;tj<4;++tj)
      #pragma unroll
      for (int r=0;r<4;++r)
        C[(size_t)(wr+ti*16+quad*4+r)*SD + wc + tj*16 + ln15] = f2bf(acc[ti][tj][r]);
}

// ---------------- K5m: MFMA PWA update: m1 = m + (sigmoid(mn@wg^T) * o) @ wo^T ----------------
__global__ __launch_bounds__(256) void k5m(
    const float* __restrict__ m_in, const unsigned short* __restrict__ mn,
    const unsigned short* __restrict__ o2,
    const unsigned short* __restrict__ wgb, const unsigned short* __restrict__ wob,
    float* __restrict__ m1_out)
{
  __shared__ unsigned short tA[128*LDSW];
  __shared__ unsigned short uC[128*LDSW];
  int i = blockIdx.y, s0 = blockIdx.x*128, t = threadIdx.x;
  int lane = t&63, w = t>>6, ln15 = lane&15, quad = lane>>4;
  int wr = (w>>1)*64, wc2 = (w&1)*32;

  { // stage mn rows (s0+r, i) -> tA
    int r = t>>1, hf = t&1;
    const unsigned short* src = mn + (((size_t)(s0+r))*N_DIM + i)*CM + hf*32;
    #pragma unroll
    for (int e=0;e<4;++e)
      *(short8*)(tA + r*LDSW + hf*32 + e*8) = *(const short8*)(src + e*8);
  }
  __syncthreads();

  short8 af[4][2];
  #pragma unroll
  for (int x=0;x<4;++x)
    #pragma unroll
    for (int kk=0;kk<2;++kk)
      af[x][kk] = *(const short8*)(tA + (wr + x*16 + ln15)*LDSW + kk*32 + quad*8);

  floatx4 mAcc[4][2];
  #pragma unroll
  for (int x=0;x<4;++x){ mAcc[x][0]=(floatx4){0,0,0,0}; mAcc[x][1]=(floatx4){0,0,0,0}; }

  for (int hc=0; hc<4; ++hc){
    floatx4 gA[4][2];
    #pragma unroll
    for (int x=0;x<4;++x){ gA[x][0]=(floatx4){0,0,0,0}; gA[x][1]=(floatx4){0,0,0,0}; }
    short8 bg[2][2];
    #pragma unroll
    for (int xj=0;xj<2;++xj)
      #pragma unroll
      for (int kk=0;kk<2;++kk)
        bg[xj][kk] = *(const short8*)(wgb + (hc*64 + wc2 + xj*16 + ln15)*CM + kk*32 + quad*8);
    #pragma unroll
    for (int kk=0;kk<2;++kk)
      #pragma unroll
      for (int x=0;x<4;++x)
        #pragma unroll
        for (int xj=0;xj<2;++xj)
          gA[x][xj] = __builtin_amdgcn_mfma_f32_16x16x32_bf16(af[x][kk], bg[xj][kk], gA[x][xj], 0,0,0);
    __syncthreads();  // prev chunk's uC reads complete
    #pragma unroll
    for (int x=0;x<4;++x)
      #pragma unroll
      for (int xj=0;xj<2;++xj)
        #pragma unroll
        for (int r=0;r<4;++r){
          int s = wr + x*16 + quad*4 + r, c = wc2 + xj*16 + ln15;
          int hd = hc*64 + c, h = hd>>5, d = hd&31;
          float gv = 1.f/(1.f+__expf(-gA[x][xj][r]));
          float ov = bf2f(o2[((size_t)(h*N_DIM + i))*SD + (size_t)(s0+s)*CH + d]);
          uC[s*LDSW + c] = f2bf(gv*ov);
        }
    __syncthreads();
    short8 au[4][2], bo[2][2];
    #pragma unroll
    for (int x=0;x<4;++x)
      #pragma unroll
      for (int kk=0;kk<2;++kk)
        au[x][kk] = *(const short8*)(uC + (wr + x*16 + ln15)*LDSW + kk*32 + quad*8);
    #pragma unroll
    for (int xj=0;xj<2;++xj)
      #pragma unroll
      for (int kk=0;kk<2;++kk)
        bo[xj][kk] = *(const short8*)(wob + (wc2 + xj*16 + ln15)*HID + hc*64 + kk*32 + quad*8);
    #pragma unroll
    for (int kk=0;kk<2;++kk)
      #pragma unroll
      for (int x=0;x<4;++x)
        #pragma unroll
        for (int xj=0;xj<2;++xj)
          mAcc[x][xj] = __builtin_amdgcn_mfma_f32_16x16x32_bf16(au[x][kk], bo[xj][kk], mAcc[x][xj], 0,0,0);
  }
  #pragma unroll
  for (int x=0;x<4;++x)
    #pragma unroll
    for (int xj=0;xj<2;++xj)
      #pragma unroll
      for (int r=0;r<4;++r){
        int s = wr + x*16 + quad*4 + r, c = wc2 + xj*16 + ln15;
        size_t gi = (((size_t)(s0+s))*N_DIM + i)*CM + c;
        m1_out[gi] = m_in[gi] + mAcc[x][xj][r];
      }
}

// ---------------- K6m: MFMA SwiGLU transition + LN + a/b projections ----------------
__global__ __launch_bounds__(256) void k6m(
    float* __restrict__ m_io, const float* __restrict__ mask,
    const float* __restrict__ lntg, const float* __restrict__ lntb,
    const unsigned short* __restrict__ fc1b, const unsigned short* __restrict__ fc2b,
    const unsigned short* __restrict__ fc3b,
    const float* __restrict__ lnog, const float* __restrict__ lnob,
    const unsigned short* __restrict__ wabb,
    unsigned short* __restrict__ a2g, unsigned short* __restrict__ b2g)
{
  __shared__ unsigned short tA[128*LDSW];
  __shared__ unsigned short uC[128*LDSW];
  __shared__ float maskL[128];
  int i = blockIdx.y, s0 = blockIdx.x*128, t = threadIdx.x;
  int lane = t&63, w = t>>6, ln15 = lane&15, quad = lane>>4;
  int wr = (w>>1)*64, wc2 = (w&1)*32;

  { // LN1 of m1 rows -> tA (bf16)
    int r = t>>1, hf = t&1;
    const float4* src = (const float4*)(m_io + (((size_t)(s0+r))*N_DIM + i)*CM + hf*32);
    float xv[32];
    #pragma unroll
    for (int e=0;e<8;++e){
      float4 x = src[e];
      xv[e*4+0]=x.x; xv[e*4+1]=x.y; xv[e*4+2]=x.z; xv[e*4+3]=x.w;
    }
    float sm = 0.f;
    #pragma unroll
    for (int e=0;e<32;++e) sm += xv[e];
    sm += __shfl_xor(sm, 1, 64);
    float mu = sm * (1.0f/64.0f);
    float vr = 0.f;
    #pragma unroll
    for (int e=0;e<32;++e){ float d = xv[e]-mu; vr += d*d; }
    vr += __shfl_xor(vr, 1, 64);
    float rs = rsqrtf(vr*(1.0f/64.0f) + 1e-5f);
    #pragma unroll
    for (int e=0;e<8;++e){
      ushort4 pk;
      pk.x = f2bf((xv[e*4+0]-mu)*rs*lntg[hf*32+e*4+0] + lntb[hf*32+e*4+0]);
      pk.y = f2bf((xv[e*4+1]-mu)*rs*lntg[hf*32+e*4+1] + lntb[hf*32+e*4+1]);
      pk.z = f2bf((xv[e*4+2]-mu)*rs*lntg[hf*32+e*4+2] + lntb[hf*32+e*4+2]);
      pk.w = f2bf((xv[e*4+3]-mu)*rs*lntg[hf*32+e*4+3] + lntb[hf*32+e*4+3]);
      *(ushort4*)(tA + r*LDSW + hf*32 + e*4) = pk;
    }
    if (t < 128) maskL[t] = mask[(size_t)(s0+t)*N_DIM + i];
  }
  __syncthreads();

  short8 af[4][2];
  #pragma unroll
  for (int x=0;x<4;++x)
    #pragma unroll
    for (int kk=0;kk<2;++kk)
      af[x][kk] = *(const short8*)(tA + (wr + x*16 + ln15)*LDSW + kk*32 + quad*8);

  floatx4 mAcc[4][2];
  #pragma unroll
  for (int x=0;x<4;++x){ mAcc[x][0]=(floatx4){0,0,0,0}; mAcc[x][1]=(floatx4){0,0,0,0}; }

  for (int hc=0; hc<4; ++hc){
    floatx4 h1A[4][2], h2A[4][2];
    #pragma unroll
    for (int x=0;x<4;++x){
      h1A[x][0]=(floatx4){0,0,0,0}; h1A[x][1]=(floatx4){0,0,0,0};
      h2A[x][0]=(floatx4){0,0,0,0}; h2A[x][1]=(floatx4){0,0,0,0};
    }
    short8 b1[2][2], b2[2][2];
    #pragma unroll
    for (int xj=0;xj<2;++xj)
      #pragma unroll
      for (int kk=0;kk<2;++kk){
        int hrow = hc*64 + wc2 + xj*16 + ln15;
        b1[xj][kk] = *(const short8*)(fc1b + hrow*CM + kk*32 + quad*8);
        b2[xj][kk] = *(const short8*)(fc2b + hrow*CM + kk*32 + quad*8);
      }
    #pragma unroll
    for (int kk=0;kk<2;++kk)
      #pragma unroll
      for (int x=0;x<4;++x)
        #pragma unroll
        for (int xj=0;xj<2;++xj){
          h1A[x][xj] = __builtin_amdgcn_mfma_f32_16x16x32_bf16(af[x][kk], b1[xj][kk], h1A[x][xj], 0,0,0);
          h2A[x][xj] = __builtin_amdgcn_mfma_f32_16x16x32_bf16(af[x][kk], b2[xj][kk], h2A[x][xj], 0,0,0);
        }
    __syncthreads();  // prev chunk's uC reads complete
    #pragma unroll
    for (int x=0;x<4;++x)
      #pragma unroll
      for (int xj=0;xj<2;++xj)
        #pragma unroll
        for (int r=0;r<4;++r){
          int s = wr + x*16 + quad*4 + r, c = wc2 + xj*16 + ln15;
          float hv = h1A[x][xj][r];
          float u = hv/(1.f+__expf(-hv)) * h2A[x][xj][r];
          uC[s*LDSW + c] = f2bf(u);
        }
    __syncthreads();
    short8 au[4][2], b3[2][2];
    #pragma unroll
    for (int x=0;x<4;++x)
      #pragma unroll
      for (int kk=0;kk<2;++kk)
        au[x][kk] = *(const short8*)(uC + (wr + x*16 + ln15)*LDSW + kk*32 + quad*8);
    #pragma unroll
    for (int xj=0;xj<2;++xj)
      #pragma unroll
      for (int kk=0;kk<2;++kk)
        b3[xj][kk] = *(const short8*)(fc3b + (wc2 + xj*16 + ln15)*HID + hc*64 + kk*32 + quad*8);
    #pragma unroll
    for (int kk=0;kk<2;++kk)
      #pragma unroll
      for (int x=0;x<4;++x)
        #pragma unroll
        for (int xj=0;xj<2;++xj)
          mAcc[x][xj] = __builtin_amdgcn_mfma_f32_16x16x32_bf16(au[x][kk], b3[xj][kk], mAcc[x][xj], 0,0,0);
  }
  __syncthreads();  // all uC/tA reads complete

  // m2 = m1 + mAcc -> global (fp32) + tA (bf16)
  #pragma unroll
  for (int x=0;x<4;++x)
    #pragma unroll
    for (int xj=0;xj<2;++xj)
      #pragma unroll
      for (int r=0;r<4;++r){
        int s = wr + x*16 + quad*4 + r, c = wc2 + xj*16 + ln15;
        size_t gi = (((size_t)(s0+s))*N_DIM + i)*CM + c;
        float m2v = m_io[gi] + mAcc[x][xj][r];
        m_io[gi] = m2v;
        tA[s*LDSW + c] = f2bf(m2v);
      }
  __syncthreads();

  { // LN2 from tA -> mo in uC
    int r = t>>1, hf = t&1;
    float xv[32];
    #pragma unroll
    for (int e=0;e<32;++e) xv[e] = bf2f(tA[r*LDSW + hf*32 + e]);
    float sm = 0.f;
    #pragma unroll
    for (int e=0;e<32;++e) sm += xv[e];
    sm += __shfl_xor(sm, 1, 64);
    float mu = sm * (1.0f/64.0f);
    float vr = 0.f;
    #pragma unroll
    for (int e=0;e<32;++e){ float d = xv[e]-mu; vr += d*d; }
    vr += __shfl_xor(vr, 1, 64);
    float rs = rsqrtf(vr*(1.0f/64.0f) + 1e-5f);
    #pragma unroll
    for (int e=0;e<8;++e){
      ushort4 pk;
      pk.x = f2bf((xv[e*4+0]-mu)*rs*lnog[hf*32+e*4+0] + lnob[hf*32+e*4+0]);
      pk.y = f2bf((xv[e*4+1]-mu)*rs*lnog[hf*32+e*4+1] + lnob[hf*32+e*4+1]);
      pk.z = f2bf((xv[e*4+2]-mu)*rs*lnog[hf*32+e*4+2] + lnob[hf*32+e*4+2]);
      pk.w = f2bf((xv[e*4+3]-mu)*rs*lnog[hf*32+e*4+3] + lnob[hf*32+e*4+3]);
      *(ushort4*)(uC + r*LDSW + hf*32 + e*4) = pk;
    }
  }
  __syncthreads();

  // GEMM3: mo @ [wa;wb]^T (K=64), masked transposed store
  floatx4 ab[4][2];
  #pragma unroll
  for (int x=0;x<4;++x){ ab[x][0]=(floatx4){0,0,0,0}; ab[x][1]=(floatx4){0,0,0,0}; }
  short8 am[4][2], bw[2][2];
  #pragma unroll
  for (int x=0;x<4;++x)
    #pragma unroll
    for (int kk=0;kk<2;++kk)
      am[x][kk] = *(const short8*)(uC + (wr + x*16 + ln15)*LDSW + kk*32 + quad*8);
  #pragma unroll
  for (int xj=0;xj<2;++xj)
    #pragma unroll
    for (int kk=0;kk<2;++kk)
      bw[xj][kk] = *(const short8*)(wabb + (wc2 + xj*16 + ln15)*CM + kk*32 + quad*8);
  #pragma unroll
  for (int kk=0;kk<2;++kk)
    #pragma unroll
    for (int x=0;x<4;++x)
      #pragma unroll
      for (int xj=0;xj<2;++xj)
        ab[x][xj] = __builtin_amdgcn_mfma_f32_16x16x32_bf16(am[x][kk], bw[xj][kk], ab[x][xj], 0,0,0);
  #pragma unroll
  for (int x=0;x<4;++x)
    #pragma unroll
    for (int xj=0;xj<2;++xj){
      int c = wc2 + xj*16 + ln15;
      int sbase = wr + x*16 + quad*4;
      ushort4 pk;
      #pragma unroll
      for (int r=0;r<4;++r) pk[r] = f2bf(ab[x][xj][r] * maskL[sbase+r]);
      unsigned short* dst = (c < 32)
        ? (a2g + ((size_t)i*COPM + c)*S_DIM + s0 + sbase)
        : (b2g + ((size_t)i*COPM + (c-32))*S_DIM + s0 + sbase);
      *(ushort4*)dst = pk;
    }
}

// ---------------- K8: outer-product GEMM + fused w_out epilogue -> z ----------------
__global__ __launch_bounds__(256) void k8_outer(
    const unsigned short* __restrict__ a2, const unsigned short* __restrict__ b2,
    const unsigned short* __restrict__ woutb, const float* __restrict__ num,
    const float* __restrict__ zin, const float* __restrict__ bout,
    float* __restrict__ zout)
{
  __shared__ unsigned short smem[16384];
  int t = threadIdx.x, lane = t&63, w = t>>6;
  int ln15 = lane&15, quad = lane>>4;
  int wr = (w>>1)*64, wc = (w&1)*64;
  int nb = blockIdx.x, mb = blockIdx.y;
  const unsigned short* A = a2 + (size_t)(mb*128)*S_DIM;
  const unsigned short* B = b2 + (size_t)(nb*128)*S_DIM;
  floatx4 acc[4][4];
  #pragma unroll
  for (int ti=0;ti<4;++ti)
    #pragma unroll
    for (int tj=0;tj<4;++tj) acc[ti][tj] = (floatx4){0.f,0.f,0.f,0.f};
  gemm_bt_core(A, B, S_DIM, S_DIM, S_DIM, smem, smem+8192, acc, wr, wc, ln15, quad);
  unsigned short* P = smem;
  #pragma unroll
  for (int ti=0;ti<4;++ti)
    #pragma unroll
    for (int tj=0;tj<4;++tj)
      #pragma unroll
      for (int r=0;r<4;++r)
        P[(wr+ti*16+quad*4+r)*128 + wc+tj*16+ln15] = f2bf(acc[ti][tj][r]);
  __syncthreads();
  int i0 = mb*4, j0 = nb*4;
  #pragma unroll
  for (int e=0; e<2; ++e){
    int czt = w*2+e;
    floatx4 acc2 = (floatx4){0.f,0.f,0.f,0.f};
    #pragma unroll 8
    for (int ks=0; ks<32; ++ks){
      short8 pa = *(const short8*)(P + (((ln15>>2)*32 + ks)<<7) + (ln15&3)*32 + quad*8);
      short8 wf = *(const short8*)(woutb + (size_t)(czt*16+ln15)*1024 + ks*32 + quad*8);
      acc2 = __builtin_amdgcn_mfma_f32_16x16x32_bf16(pa, wf, acc2, 0, 0, 0);
    }
    #pragma unroll
    for (int r2=0;r2<4;++r2){
      int p = quad*4+r2, ic = p>>2, jc = p&3;
      int i = i0+ic, j = j0+jc;
      float nv = num[(size_t)i*N_DIM+j];
      size_t zi = ((size_t)i*N_DIM + j)*CZ + czt*16 + ln15;
      zout[zi] = zin[zi] + acc2[r2]*(1.0f/nv) + bout[czt*16+ln15];
    }
  }
}

extern "C" void kernel_launch(void* const* d_in, const int* in_sizes, int n_in,
                              void* d_out, int out_size, void* d_ws, size_t ws_size,
                              hipStream_t stream)
{
  const float* z    = (const float*)d_in[0];
  const float* m    = (const float*)d_in[1];
  const float* tm   = (const float*)d_in[2];
  const float* mask = (const float*)d_in[3];
  const float* lnzg = (const float*)d_in[4];
  const float* lnzb = (const float*)d_in[5];
  const float* wz   = (const float*)d_in[6];
  const float* lnmg = (const float*)d_in[7];
  const float* lnmb = (const float*)d_in[8];
  const float* wm   = (const float*)d_in[9];
  const float* wg   = (const float*)d_in[10];
  const float* wo   = (const float*)d_in[11];
  const float* lntg = (const float*)d_in[12];
  const float* lntb = (const float*)d_in[13];
  const float* fc1  = (const float*)d_in[14];
  const float* fc2  = (const float*)d_in[15];
  const float* fc3  = (const float*)d_in[16];
  const float* lnog = (const float*)d_in[17];
  const float* lnob = (const float*)d_in[18];
  const float* wa   = (const float*)d_in[19];
  const float* wb   = (const float*)d_in[20];
  const float* wout = (const float*)d_in[21];
  const float* bout = (const float*)d_in[22];

  float* zout = (float*)d_out;
  float* mout = zout + (size_t)N_DIM*N_DIM*CZ;

  // z-region of d_out doubles as scratch for buffers dead before k8 writes z:
  char* zs = (char*)d_out;
  unsigned short* mn     = (unsigned short*)zs;               // 50,331,648 B
  float*          logits = (float*)(zs + 50331648);           //  4,718,592 B
  unsigned short* watt   = (unsigned short*)(zs + 55050240);  //  2,359,296 B
  unsigned short* W      = (unsigned short*)(zs + 57409536);  // bf16 weights (dead before k8)
  unsigned short* wgb  = W;          // 16384
  unsigned short* wob  = W + 16384;  // 16384
  unsigned short* fc1b = W + 32768;  // 16384
  unsigned short* fc2b = W + 49152;  // 16384
  unsigned short* fc3b = W + 65536;  // 16384
  unsigned short* wabb = W + 81920;  //  4096

  char* ws = (char*)d_ws;
  unsigned short* v2    = (unsigned short*)ws;                // 201,326,592 B
  unsigned short* o2    = (unsigned short*)(ws + 201326592);  // 201,326,592 B
  float*          num   = (float*)(ws + 402653184);           //     589,824 B
  unsigned short* woutb = (unsigned short*)(ws + 403243008);  //     262,144 B
  unsigned short* a2 = v2;                                    // alias: v2 dead after k4
  unsigned short* b2 = v2 + (size_t)MO*S_DIM;

  kcvt<<<64, 256, 0, stream>>>(wg,  wgb,  16384);
  kcvt<<<64, 256, 0, stream>>>(wo,  wob,  16384);
  kcvt<<<64, 256, 0, stream>>>(fc1, fc1b, 16384);
  kcvt<<<64, 256, 0, stream>>>(fc2, fc2b, 16384);
  kcvt<<<64, 256, 0, stream>>>(fc3, fc3b, 16384);
  kcvt<<<8,  256, 0, stream>>>(wa,  wabb, 2048);
  kcvt<<<8,  256, 0, stream>>>(wb,  wabb+2048, 2048);
  kcvt<<<512,256, 0, stream>>>(wout, woutb, 131072);

  k1_logits  <<<36864, 256, 0, stream>>>(z, tm, lnzg, lnzb, wz, logits);
  k2_softmax <<<768, 256, 0, stream>>>(logits, watt);
  k3_lnm_v   <<<dim3(24,1024), 256, 0, stream>>>(m, lnmg, lnmb, wm, mn, v2);
  k7_num     <<<dim3(24,24), 256, 0, stream>>>(mask, num);
  k4_attn    <<<dim3(256,3,8), 256, 0, stream>>>(watt, v2, o2);
  k5m        <<<dim3(8,384), 256, 0, stream>>>(m, mn, o2, wgb, wob, mout);
  k6m        <<<dim3(8,384), 256, 0, stream>>>(mout, mask, lntg, lntb, fc1b, fc2b, fc3b,
                                               lnog, lnob, wabb, a2, b2);
  k8_outer   <<<dim3(96,96), 256, 0, stream>>>(a2, b2, woutb, num, z, bout, zout);
}